// Round 7
// baseline (170.476 us; speedup 1.0000x reference)
//
#include <hip/hip_runtime.h>

// Problem: B=64, H=W=512 fp32. out = x + (f - conv3x3(x,k_b)) / 6, zero pad,
// cross-correlation (no kernel flip).
//
// R10 (post-mortem of R9): warm dispatches (x+f fully L3-resident, ZERO HBM
// fetch) run at the same speed as cold ones in every round -> the limiter is
// the VECTOR-MEMORY PIPE (per-CU outstanding-request capacity x latency,
// ~6.3 TB/s of L1-level traffic), not HBM. Cross-round: bytes-through-pipe /
// dur = 6.26 (R4), 5.4 (R9), 3.75 (R8, starved) TB/s. So: remove bytes from
// the VMEM pipe. The 3x re-read of x moves to LDS (separate DS pipe/queues).
//  - Block = 8 output rows. Stage 10 x-rows (20 KB LDS, 8 blocks/CU) in 5
//    fully-coalesced 1024B-per-wave sweeps; out-of-image rows zero-filled
//    (restores zero-pad semantics with FULL weights, no weight-zero trick).
//  - f for each wave's 2 rows preloaded BEFORE __syncthreads (latency hides
//    under the barrier); sched_barrier(0) pins all 9 global loads up top.
//  - Compute: quads from LDS ds_read_b128 (16B/lane, conflict-free), halos
//    via R9's proven 6-shfl pattern, split-quad stores (contiguous 1024B).
// VMEM traffic: 52 KB/block x 4096 = 213 MB vs R9's 335 MB (0.64x).
#define BB 64
#define HH 512
#define WW 512
#define TR 8                          // output rows per block
#define NBLOCKS (BB * HH / TR)        // 4096

struct Q { float4 v; float l, r; };   // quad + left/right halo floats

// cross-correlation accumulate: (w0,w1,w2) multiply cols j-1,j,j+1
__device__ __forceinline__ void accumq(float4& q, const Q& w,
                                       float w0, float w1, float w2) {
    q.x += w0 * w.l   + w1 * w.v.x + w2 * w.v.y;
    q.y += w0 * w.v.x + w1 * w.v.y + w2 * w.v.z;
    q.z += w0 * w.v.y + w1 * w.v.z + w2 * w.v.w;
    q.w += w0 * w.v.z + w1 * w.v.w + w2 * w.r;
}

__global__ __launch_bounds__(256) void jacobi_v10_kernel(
    const float* __restrict__ x,
    const float* __restrict__ f,
    const float* __restrict__ k,
    float* __restrict__ out)
{
    __shared__ float tile[(TR + 2) * WW];          // 20480 B

    const int tid  = threadIdx.x;
    const int lane = tid & 63;
    const int wv   = tid >> 6;

    // 64 tiles per image -> b scalar (SGPR) by construction.
    const int b  = blockIdx.x >> 6;
    const int tb = blockIdx.x & 63;
    const int r0 = tb << 3;                        // first output row of tile

    const size_t img = (size_t)b * (HH * WW);
    const float* xb = x + img;
    const float* fb = f + img;
    float*       ob = out + img;

    const float* kb = k + b * 9;                   // scalar -> s_load
    const float k00 = kb[0], k01 = kb[1], k02 = kb[2];
    const float k10 = kb[3], k11 = kb[4], k12 = kb[5];
    const float k20 = kb[6], k21 = kb[7], k22 = kb[8];

    const int col = lane << 2;                     // quad A col; quad B = +256

    // ---- global load block: 5 staging sweeps + 4 f quads, all pinned up top
    float4 sv[5];
    int    fl[5];
    #pragma unroll
    for (int s = 0; s < 5; ++s) {
        const int flat = ((s << 8) + tid) << 2;    // float index in tile
        const int trow = flat >> 9;                // tile row 0..9
        const int tcol = flat & 511;
        const int gr   = r0 - 1 + trow;            // image row (may be OOB)
        fl[s] = flat;
        sv[s] = ((unsigned)gr < (unsigned)HH)
                    ? *(const float4*)(xb + (size_t)gr * WW + tcol)
                    : make_float4(0.f, 0.f, 0.f, 0.f);
    }
    const int i0 = r0 + (wv << 1);                 // this wave's first row
    const float* pf0 = fb + (size_t)i0 * WW + col;
    const float* pf1 = pf0 + WW;
    const float4 f0a = *(const float4*)pf0, f0b = *(const float4*)(pf0 + 256);
    const float4 f1a = *(const float4*)pf1, f1b = *(const float4*)(pf1 + 256);
    __builtin_amdgcn_sched_barrier(0);             // no sinking below

    #pragma unroll
    for (int s = 0; s < 5; ++s)
        *(float4*)(tile + fl[s]) = sv[s];
    __syncthreads();

    const float inv6 = 1.f / 6.f;
    #pragma unroll
    for (int j = 0; j < 2; ++j) {
        const int orow = (wv << 1) + j;            // output row within tile
        // stencil tile rows: orow, orow+1, orow+2 (tile row t = image r0-1+t)
        float4 xa[3], xq[3];
        #pragma unroll
        for (int t = 0; t < 3; ++t) {
            const float* lp = tile + (orow + t) * WW + col;
            xa[t] = *(const float4*)lp;            // ds_read_b128
            xq[t] = *(const float4*)(lp + 256);
        }
        // halos: entirely via shfl (R9-proven pattern)
        Q A[3], Bq[3];
        #pragma unroll
        for (int t = 0; t < 3; ++t) {
            const float a_l  = __shfl_up(xa[t].w, 1);
            const float a_r  = __shfl_down(xa[t].x, 1);
            const float b_l  = __shfl_up(xq[t].w, 1);
            const float b_r  = __shfl_down(xq[t].x, 1);
            const float aw63 = __shfl(xa[t].w, 63);   // float[255]
            const float bx0  = __shfl(xq[t].x, 0);    // float[256]
            A[t].v  = xa[t];
            Bq[t].v = xq[t];
            A[t].l  = (lane == 0)  ? 0.f  : a_l;      // image left edge pad
            A[t].r  = (lane == 63) ? bx0  : a_r;      // col 256 from quad B
            Bq[t].l = (lane == 0)  ? aw63 : b_l;      // col 255 from quad A
            Bq[t].r = (lane == 63) ? 0.f  : b_r;      // image right edge pad
        }

        float4 qa = make_float4(0.f, 0.f, 0.f, 0.f);
        float4 qb = make_float4(0.f, 0.f, 0.f, 0.f);
        accumq(qa, A[0],  k00, k01, k02);          // stencil row i-1
        accumq(qa, A[1],  k10, k11, k12);          // stencil row i
        accumq(qa, A[2],  k20, k21, k22);          // stencil row i+1
        accumq(qb, Bq[0], k00, k01, k02);
        accumq(qb, Bq[1], k10, k11, k12);
        accumq(qb, Bq[2], k20, k21, k22);

        const float4 fa = j ? f1a : f0a;
        const float4 fq = j ? f1b : f0b;
        const float4 ca = A[1].v;
        const float4 cb = Bq[1].v;
        float4 oa, oq;
        oa.x = ca.x + (fa.x - qa.x) * inv6;
        oa.y = ca.y + (fa.y - qa.y) * inv6;
        oa.z = ca.z + (fa.z - qa.z) * inv6;
        oa.w = ca.w + (fa.w - qa.w) * inv6;
        oq.x = cb.x + (fq.x - qb.x) * inv6;
        oq.y = cb.y + (fq.y - qb.y) * inv6;
        oq.z = cb.z + (fq.z - qb.z) * inv6;
        oq.w = cb.w + (fq.w - qb.w) * inv6;

        float* po = ob + (size_t)(i0 + j) * WW + col;
        *(float4*)po         = oa;                 // contiguous 1024 B
        *(float4*)(po + 256) = oq;                 // contiguous 1024 B
    }
}

extern "C" void kernel_launch(void* const* d_in, const int* in_sizes, int n_in,
                              void* d_out, int out_size, void* d_ws, size_t ws_size,
                              hipStream_t stream) {
    const float* x  = (const float*)d_in[0];
    const float* f  = (const float*)d_in[1];
    const float* kk = (const float*)d_in[2];
    float* out = (float*)d_out;

    jacobi_v10_kernel<<<NBLOCKS, 256, 0, stream>>>(x, f, kk, out);
}